// Round 1
// baseline (726.380 us; speedup 1.0000x reference)
//
#include <hip/hip_runtime.h>
#include <hip/hip_bf16.h>
#include <math.h>

#define WAVE 64

// ---------------- CSR build ----------------
__global__ void count_deg(const int* __restrict__ dst, int* __restrict__ deg, int E) {
    int e = blockIdx.x * 256 + threadIdx.x;
    if (e < E) atomicAdd(&deg[dst[e]], 1);
}

// 256-element block scan (Hillis-Steele). part[i] = exclusive prefix within block,
// bsums[b] = block total.
__global__ void scan_block(const int* __restrict__ in, int* __restrict__ part,
                           int* __restrict__ bsums, int n) {
    __shared__ int tmp[256];
    int tid = threadIdx.x;
    int i = blockIdx.x * 256 + tid;
    int v = (i < n) ? in[i] : 0;
    tmp[tid] = v;
    __syncthreads();
    for (int o = 1; o < 256; o <<= 1) {
        int t = (tid >= o) ? tmp[tid - o] : 0;
        __syncthreads();
        tmp[tid] += t;
        __syncthreads();
    }
    if (i < n) part[i] = tmp[tid] - v;
    if (tid == 255) bsums[blockIdx.x] = tmp[255];
}

// exclusive scan of up to 256 values in place
__global__ void scan_small(int* __restrict__ data, int nb) {
    __shared__ int tmp[256];
    int tid = threadIdx.x;
    int v = (tid < nb) ? data[tid] : 0;
    tmp[tid] = v;
    __syncthreads();
    for (int o = 1; o < 256; o <<= 1) {
        int t = (tid >= o) ? tmp[tid - o] : 0;
        __syncthreads();
        tmp[tid] += t;
        __syncthreads();
    }
    if (tid < nb) data[tid] = tmp[tid] - v;
}

__global__ void add_offsets(const int* __restrict__ part, const int* __restrict__ bpref,
                            int* __restrict__ offs, int n, int Etot) {
    int i = blockIdx.x * 256 + threadIdx.x;
    if (i < n) offs[i] = part[i] + bpref[blockIdx.x];
    if (blockIdx.x == 0 && threadIdx.x == 0) offs[n] = Etot;
}

__global__ void scatter_edges(const int* __restrict__ src, const int* __restrict__ dst,
                              int* __restrict__ cursor, int* __restrict__ csr_src, int E) {
    int e = blockIdx.x * 256 + threadIdx.x;
    if (e < E) {
        int p = atomicAdd(&cursor[dst[e]], 1);
        csr_src[p] = src[e];
    }
}

// ---------------- GEMM: H = X[n,128] @ W[128,128] ----------------
// W staged in LDS (64KB). 64 rows/block, 256 threads, each thread: 8 rows x 4 cols.
__global__ __launch_bounds__(256) void gemm128(const float* __restrict__ X,
                                               const float* __restrict__ W,
                                               float* __restrict__ H, int n) {
    __shared__ float Ws[128 * 128];
    int tid = threadIdx.x;
    const float4* W4 = (const float4*)W;
    float4* Ws4 = (float4*)Ws;
#pragma unroll
    for (int i = 0; i < 16; ++i) Ws4[i * 256 + tid] = W4[i * 256 + tid];
    __syncthreads();

    int tx = tid & 31;        // col quad: cols 4*tx .. 4*tx+3
    int ty = tid >> 5;        // row group: rows ty*8 .. ty*8+7
    int row0 = blockIdx.x * 64 + ty * 8;
    float4 acc[8];
#pragma unroll
    for (int r = 0; r < 8; ++r) acc[r] = make_float4(0.f, 0.f, 0.f, 0.f);

    const float4* X4 = (const float4*)X;
    for (int k4 = 0; k4 < 32; ++k4) {
        float4 xv[8];
#pragma unroll
        for (int r = 0; r < 8; ++r) {
            int row = row0 + r;
            xv[r] = (row < n) ? X4[(size_t)row * 32 + k4] : make_float4(0.f, 0.f, 0.f, 0.f);
        }
#pragma unroll
        for (int kk = 0; kk < 4; ++kk) {
            float4 wv = Ws4[(k4 * 4 + kk) * 32 + tx];
#pragma unroll
            for (int r = 0; r < 8; ++r) {
                float xk = (kk == 0) ? xv[r].x : (kk == 1) ? xv[r].y : (kk == 2) ? xv[r].z : xv[r].w;
                acc[r].x = fmaf(xk, wv.x, acc[r].x);
                acc[r].y = fmaf(xk, wv.y, acc[r].y);
                acc[r].z = fmaf(xk, wv.z, acc[r].z);
                acc[r].w = fmaf(xk, wv.w, acc[r].w);
            }
        }
    }
#pragma unroll
    for (int r = 0; r < 8; ++r) {
        int row = row0 + r;
        if (row < n) ((float4*)H)[(size_t)row * 32 + tx] = acc[r];
    }
}

// ---------------- per-node attention dots: as_[i] = h_i . a_src, ad_[i] = h_i . a_dst
__global__ void att_dots(const float* __restrict__ H, const float* __restrict__ a_s,
                         const float* __restrict__ a_d, float* __restrict__ as_,
                         float* __restrict__ ad_, int n) {
    int i = blockIdx.x * 256 + threadIdx.x;
    if (i >= n) return;
    const float4* h4 = (const float4*)H + (size_t)i * 32;
    const float4* A = (const float4*)a_s;
    const float4* B = (const float4*)a_d;
    float s = 0.f, d = 0.f;
#pragma unroll
    for (int k = 0; k < 32; ++k) {
        float4 h = h4[k];
        float4 a = A[k];
        float4 b = B[k];
        s = fmaf(h.x, a.x, fmaf(h.y, a.y, fmaf(h.z, a.z, fmaf(h.w, a.w, s))));
        d = fmaf(h.x, b.x, fmaf(h.y, b.y, fmaf(h.z, b.z, fmaf(h.w, b.w, d))));
    }
    as_[i] = s;
    ad_[i] = d;
}

__device__ __forceinline__ float leaky02(float x) { return x > 0.f ? x : 0.2f * x; }

// ---------------- GAT aggregation: wave per dst node ----------------
// out[i] = sum_j alpha_ij * h[src_j] + bias  (self-loop included analytically)
// act: 0 = none, 1 = ELU
__global__ __launch_bounds__(256) void gat_aggregate(const float* __restrict__ h,
                                                     const float* __restrict__ as_,
                                                     const float* __restrict__ ad_,
                                                     const int* __restrict__ csr_src,
                                                     const int* __restrict__ offs,
                                                     const float* __restrict__ bias,
                                                     float* __restrict__ out, int n, int act) {
    int node = blockIdx.x * 4 + (threadIdx.x >> 6);
    int lane = threadIdx.x & 63;
    if (node >= n) return;
    int beg = offs[node], end = offs[node + 1];
    float adn = ad_[node];
    float e_self = leaky02(as_[node] + adn);

    // pass 1: max
    float m = e_self;
    for (int j = beg + lane; j < end; j += WAVE) {
        int s = csr_src[j];
        m = fmaxf(m, leaky02(as_[s] + adn));
    }
#pragma unroll
    for (int o = 32; o > 0; o >>= 1) m = fmaxf(m, __shfl_xor(m, o, WAVE));

    // pass 2: sum of exp
    float ssum = 0.f;
    for (int j = beg + lane; j < end; j += WAVE) {
        int s = csr_src[j];
        ssum += __expf(leaky02(as_[s] + adn) - m);
    }
#pragma unroll
    for (int o = 32; o > 0; o >>= 1) ssum += __shfl_xor(ssum, o, WAVE);
    ssum += __expf(e_self - m);
    float inv_s = 1.f / ssum;

    // pass 3: weighted gather. lane owns features 2*lane, 2*lane+1
    float w_self = __expf(e_self - m) * inv_s;
    float2 hv = ((const float2*)(h + (size_t)node * 128))[lane];
    float2 acc;
    acc.x = w_self * hv.x;
    acc.y = w_self * hv.y;
    for (int j = beg; j < end; ++j) {
        int s = csr_src[j];
        float w = __expf(leaky02(as_[s] + adn) - m) * inv_s;
        float2 v = ((const float2*)(h + (size_t)s * 128))[lane];
        acc.x = fmaf(w, v.x, acc.x);
        acc.y = fmaf(w, v.y, acc.y);
    }
    float2 b = ((const float2*)bias)[lane];
    float ox = acc.x + b.x;
    float oy = acc.y + b.y;
    if (act == 1) {
        ox = ox > 0.f ? ox : expm1f(ox);
        oy = oy > 0.f ? oy : expm1f(oy);
    }
    ((float2*)(out + (size_t)node * 128))[lane] = make_float2(ox, oy);
}

// ---------------- energy MLP: wave per node, HP (<=64) active lanes ----------------
__global__ __launch_bounds__(256) void energy_kernel(const float* __restrict__ X,
                                                     const float* __restrict__ Wp1,
                                                     const float* __restrict__ bp1,
                                                     const float* __restrict__ Wp2,
                                                     const float* __restrict__ bp2,
                                                     float* __restrict__ energy, int n, int HP) {
    int node = blockIdx.x * 4 + (threadIdx.x >> 6);
    int lane = threadIdx.x & 63;
    if (node >= n) return;
    float v = 0.f;
    if (lane < HP) {
        const float* xr = X + (size_t)node * 128;
        float acc = 0.f;
        for (int k = 0; k < 128; ++k) acc = fmaf(xr[k], Wp1[k * HP + lane], acc);
        float hc = acc + bp1[lane];
        hc = hc > 0.f ? hc : 0.f;
        v = hc * Wp2[lane];
    }
#pragma unroll
    for (int o = 32; o > 0; o >>= 1) v += __shfl_xor(v, o, WAVE);
    if (lane == 0) energy[node] = v + bp2[0];
}

// ---------------- segment softmax pooling: block per segment ----------------
__global__ __launch_bounds__(256) void seg_pool(const float* __restrict__ X,
                                                const float* __restrict__ energy,
                                                const int* __restrict__ node_pos,
                                                float* __restrict__ pooled) {
    int g = blockIdx.x;
    int beg = node_pos[g], end = node_pos[g + 1];
    __shared__ float red[256];
    int tid = threadIdx.x;

    float m = -INFINITY;
    for (int i = beg + tid; i < end; i += 256) m = fmaxf(m, energy[i]);
    red[tid] = m;
    __syncthreads();
    for (int o = 128; o > 0; o >>= 1) {
        if (tid < o) red[tid] = fmaxf(red[tid], red[tid + o]);
        __syncthreads();
    }
    m = red[0];
    __syncthreads();

    float s = 0.f;
    for (int i = beg + tid; i < end; i += 256) s += __expf(energy[i] - m);
    red[tid] = s;
    __syncthreads();
    for (int o = 128; o > 0; o >>= 1) {
        if (tid < o) red[tid] += red[tid + o];
        __syncthreads();
    }
    s = red[0];
    __syncthreads();
    float inv = (end > beg) ? 1.f / s : 0.f;

    int c = tid & 127, half = tid >> 7;
    float acc = 0.f;
    for (int i = beg + half; i < end; i += 2) {
        float w = __expf(energy[i] - m) * inv;
        acc = fmaf(w, X[(size_t)i * 128 + c], acc);
    }
    red[tid] = acc;
    __syncthreads();
    if (tid < 128) pooled[(size_t)g * 128 + c] = red[tid] + red[tid + 128];
}

// ---------------- classifier: out[G,C] = pooled[G,128] @ Wl[128,C] + bl ----------------
// block: 256 threads, 8 segments; grid (ceil(C/256), G/8)
__global__ __launch_bounds__(256) void classifier(const float* __restrict__ pooled,
                                                  const float* __restrict__ Wl,
                                                  const float* __restrict__ bl,
                                                  float* __restrict__ out, int G, int C) {
    __shared__ float P[8 * 128];
    int tid = threadIdx.x;
    int j0 = blockIdx.y * 8;
    for (int i = tid; i < 8 * 128; i += 256) {
        int idx = j0 * 128 + i;
        P[i] = (idx < G * 128) ? pooled[idx] : 0.f;
    }
    __syncthreads();
    int c = blockIdx.x * 256 + tid;
    if (c >= C) return;
    float bias = bl[c];
    float acc[8];
#pragma unroll
    for (int jj = 0; jj < 8; ++jj) acc[jj] = bias;
    for (int k = 0; k < 128; ++k) {
        float w = Wl[k * C + c];
#pragma unroll
        for (int jj = 0; jj < 8; ++jj) acc[jj] = fmaf(P[jj * 128 + k], w, acc[jj]);
    }
#pragma unroll
    for (int jj = 0; jj < 8; ++jj) {
        int j = j0 + jj;
        if (j < G) out[(size_t)j * C + c] = acc[jj];
    }
}

extern "C" void kernel_launch(void* const* d_in, const int* in_sizes, int n_in,
                              void* d_out, int out_size, void* d_ws, size_t ws_size,
                              hipStream_t stream) {
    const float* cfg_nodes = (const float*)d_in[0];
    const int* rel = (const int*)d_in[1];
    const int* node_pos = (const int*)d_in[2];
    const float* W_g1 = (const float*)d_in[3];
    const float* att_src1 = (const float*)d_in[4];
    const float* att_dst1 = (const float*)d_in[5];
    const float* b_g1 = (const float*)d_in[6];
    const float* W_g2 = (const float*)d_in[7];
    const float* att_src2 = (const float*)d_in[8];
    const float* att_dst2 = (const float*)d_in[9];
    const float* b_g2 = (const float*)d_in[10];
    const float* Wp1 = (const float*)d_in[11];
    const float* bp1 = (const float*)d_in[12];
    const float* Wp2 = (const float*)d_in[13];
    const float* bp2 = (const float*)d_in[14];
    const float* Wl = (const float*)d_in[15];
    const float* bl = (const float*)d_in[16];

    const int N = in_sizes[0] / 128;
    const int E = in_sizes[1] / 2;
    const int G = in_sizes[2] - 1;
    const int HP = in_sizes[12];
    const int C = out_size / G;

    const int* srcArr = rel;
    const int* dstArr = rel + E;

    // workspace carve (256B aligned)
    char* w = (char*)d_ws;
    auto carve = [&](size_t bytes) -> char* {
        char* p = w;
        w += (bytes + 255) & ~(size_t)255;
        return p;
    };
    float* bufA = (float*)carve((size_t)N * 128 * 4);   // h1 / h2
    float* bufB = (float*)carve((size_t)N * 128 * 4);   // x2 / x3
    float* asv = (float*)carve((size_t)N * 4);
    float* adv = (float*)carve((size_t)N * 4);
    float* energy = (float*)carve((size_t)N * 4);
    int* deg = (int*)carve((size_t)N * 4);
    int* offs = (int*)carve((size_t)(N + 1) * 4);
    int* cursor = (int*)carve((size_t)N * 4);
    int* csr_src = (int*)carve((size_t)E * 4);
    int* bsums = (int*)carve(1024);
    float* pooled = (float*)carve((size_t)G * 128 * 4);

    const int nbN = (N + 255) / 256;
    const int nbE = (E + 255) / 256;

    // ---- CSR build (by dst) ----
    hipMemsetAsync(deg, 0, (size_t)N * 4, stream);
    count_deg<<<nbE, 256, 0, stream>>>(dstArr, deg, E);
    scan_block<<<nbN, 256, 0, stream>>>(deg, offs, bsums, N);
    scan_small<<<1, 256, 0, stream>>>(bsums, nbN);
    add_offsets<<<nbN, 256, 0, stream>>>(offs, bsums, offs, N, E);
    hipMemcpyAsync(cursor, offs, (size_t)N * 4, hipMemcpyDeviceToDevice, stream);
    scatter_edges<<<nbE, 256, 0, stream>>>(srcArr, dstArr, cursor, csr_src, E);

    // ---- GAT layer 1 ----
    gemm128<<<(N + 63) / 64, 256, 0, stream>>>(cfg_nodes, W_g1, bufA, N);
    att_dots<<<nbN, 256, 0, stream>>>(bufA, att_src1, att_dst1, asv, adv, N);
    gat_aggregate<<<(N + 3) / 4, 256, 0, stream>>>(bufA, asv, adv, csr_src, offs, b_g1, bufB, N, 1);

    // ---- GAT layer 2 ----
    gemm128<<<(N + 63) / 64, 256, 0, stream>>>(bufB, W_g2, bufA, N);
    att_dots<<<nbN, 256, 0, stream>>>(bufA, att_src2, att_dst2, asv, adv, N);
    gat_aggregate<<<(N + 3) / 4, 256, 0, stream>>>(bufA, asv, adv, csr_src, offs, b_g2, bufB, N, 0);

    // ---- pooling + classifier ----
    energy_kernel<<<(N + 3) / 4, 256, 0, stream>>>(bufB, Wp1, bp1, Wp2, bp2, energy, N, HP);
    seg_pool<<<G, 256, 0, stream>>>(bufB, energy, node_pos, pooled);
    classifier<<<dim3((C + 255) / 256, (G + 7) / 8), 256, 0, stream>>>(pooled, Wl, bl, (float*)d_out, G, C);
}